// Round 1
// baseline (316.857 us; speedup 1.0000x reference)
//
#include <hip/hip_runtime.h>
#include <stdint.h>

// Problem constants
#define NROWS 8192
#define DIN   512
#define HIDN  1024
#define EMBN  64
#define NCONS 62      // EMB - N_EFF
#define NCLS  16
#define MARGINF 0.01f

typedef unsigned short u16;
typedef __attribute__((ext_vector_type(8))) short short8;   // 8 bf16 (4 VGPRs)
typedef __attribute__((ext_vector_type(4))) float floatx4;  // 4 fp32 acc

__device__ __forceinline__ u16 f32_to_bf16(float f) {
  union { float f; uint32_t u; } x; x.f = f;
  uint32_t u = x.u;
  uint32_t r = (u + 0x7FFFu + ((u >> 16) & 1u)) >> 16;  // RNE
  return (u16)r;
}

__device__ __forceinline__ float fast_tanh(float x) {
  float xc = fminf(fmaxf(x, -10.f), 10.f);     // clamp: avoid inf/inf
  float e = __expf(2.f * xc);
  return (e - 1.f) * __builtin_amdgcn_rcpf(e + 1.f);
}

// ---------------------------------------------------------------------------
// bf16 MFMA GEMM: C[M,N] = act(A[M,K] @ B[K,N] + bias), B given TRANSPOSED
// (Bt is N x K row-major, bf16). A is M x K row-major bf16.
// BK=32 (one 16x16x32 MFMA K-step). 256 threads = 4 waves, waves 2x2.
// Verified layouts (learn_hip m89/m91/m120):
//   A-frag: A[m=lane&15][k=quad*8+j]; B-frag: B[k=quad*8+j][n=lane&15]
//   C/D:    col=lane&15, row=quad*4+reg
// Staging: global_load_lds width=16, LDS dest = wave-uniform base + lane*16.
// ---------------------------------------------------------------------------
template<int BM, int BN, bool TANH, bool WF32, bool WBF>
__global__ __launch_bounds__(256)
void gemm_bt(const u16* __restrict__ A, const u16* __restrict__ Bt,
             const float* __restrict__ bias,
             float* __restrict__ Cf, u16* __restrict__ Cbf,
             const int N, const int K)
{
  constexpr int BK = 32;
  static_assert(BM % 32 == 0 && BN % 32 == 0, "");
  __shared__ u16 lA[BM * BK];
  __shared__ u16 lB[BN * BK];

  const int tid  = threadIdx.x;
  const int wave = tid >> 6;
  const int lane = tid & 63;
  const int quad = lane >> 4;
  const int l15  = lane & 15;

  const int m0 = blockIdx.y * BM;
  const int n0 = blockIdx.x * BN;

  constexpr int SM = BM / 32;   // 16x16 subtiles per wave (m)
  constexpr int SN = BN / 32;   // 16x16 subtiles per wave (n)
  const int wm = wave >> 1;     // 0..1
  const int wn = wave & 1;      // 0..1

  constexpr int UA = BM / 16;   // staging units (16 rows x 32 k = 1KB each)
  constexpr int UB = BN / 16;
  const int srow = lane >> 2;        // 0..15 within unit
  const int scol = (lane & 3) << 3;  // 0,8,16,24

  floatx4 acc[SM][SN];
#pragma unroll
  for (int i = 0; i < SM; ++i)
#pragma unroll
    for (int j = 0; j < SN; ++j)
      acc[i][j] = (floatx4){0.f, 0.f, 0.f, 0.f};

  for (int k0 = 0; k0 < K; k0 += BK) {
    __syncthreads();   // previous iteration's LDS reads complete
    for (int u = wave; u < UA + UB; u += 4) {
      const u16* g;
      u16* l;
      if (u < UA) {
        g = A + (size_t)(m0 + u * 16 + srow) * K + (k0 + scol);
        l = lA + u * (16 * BK);
      } else {
        const int v = u - UA;
        g = Bt + (size_t)(n0 + v * 16 + srow) * K + (k0 + scol);
        l = lB + v * (16 * BK);
      }
      __builtin_amdgcn_global_load_lds(
          (const __attribute__((address_space(1))) void*)g,
          (__attribute__((address_space(3))) void*)l, 16, 0, 0);
    }
    __syncthreads();   // compiler emits vmcnt(0) drain before s_barrier

    short8 af[SM], bfr[SN];
#pragma unroll
    for (int i = 0; i < SM; ++i)
      af[i] = *(const short8*)(lA + (wm * (BM / 2) + i * 16 + l15) * BK + quad * 8);
#pragma unroll
    for (int j = 0; j < SN; ++j)
      bfr[j] = *(const short8*)(lB + (wn * (BN / 2) + j * 16 + l15) * BK + quad * 8);
#pragma unroll
    for (int i = 0; i < SM; ++i)
#pragma unroll
      for (int j = 0; j < SN; ++j)
        acc[i][j] = __builtin_amdgcn_mfma_f32_16x16x32_bf16(af[i], bfr[j], acc[i][j], 0, 0, 0);
  }

  const int mb = m0 + wm * (BM / 2);
  const int nb = n0 + wn * (BN / 2);
#pragma unroll
  for (int i = 0; i < SM; ++i) {
#pragma unroll
    for (int j = 0; j < SN; ++j) {
      const int col = nb + j * 16 + l15;
      const float bv = bias[col];
#pragma unroll
      for (int r = 0; r < 4; ++r) {
        const int row = mb + i * 16 + quad * 4 + r;
        float v = acc[i][j][r] + bv;
        if constexpr (TANH) v = fast_tanh(v);
        const size_t o = (size_t)row * N + col;
        if constexpr (WF32) Cf[o] = v;
        if constexpr (WBF)  Cbf[o] = f32_to_bf16(v);
      }
    }
  }
}

// ---------------------------------------------------------------------------
// Weight transposes (K x N fp32 -> N x K bf16), LDS 32x32 tiles; block 0 also
// zeroes the accumulator slab (runs before any atomics use it).
// blocks: [0,512) W1(512x1024), [512,1024) W4(1024x512),
//         [1024,1088) W2(1024x64), [1088,1152) W3(64x1024)
// ---------------------------------------------------------------------------
__global__ __launch_bounds__(256)
void prep_weights(const float* __restrict__ W1, const float* __restrict__ W4,
                  const float* __restrict__ W2, const float* __restrict__ W3,
                  u16* __restrict__ W1T, u16* __restrict__ W4T,
                  u16* __restrict__ W2T, u16* __restrict__ W3T,
                  float* __restrict__ accz, int accz_words)
{
  const int b = blockIdx.x;
  if (b == 0) {
    for (int i = threadIdx.x; i < accz_words; i += 256) accz[i] = 0.f;
  }
  const float* in; u16* out; int K, N, t;
  if (b < 512)       { in = W1; out = W1T; K = 512;  N = 1024; t = b; }
  else if (b < 1024) { in = W4; out = W4T; K = 1024; N = 512;  t = b - 512; }
  else if (b < 1088) { in = W2; out = W2T; K = 1024; N = 64;   t = b - 1024; }
  else               { in = W3; out = W3T; K = 64;   N = 1024; t = b - 1088; }
  const int tiles_n = N >> 5;
  const int tk = t / tiles_n, tn = t % tiles_n;

  __shared__ float tile[32][33];
  const int r = threadIdx.x >> 5, c = threadIdx.x & 31;
  for (int rr = r; rr < 32; rr += 8)
    tile[rr][c] = in[(size_t)(tk * 32 + rr) * N + (tn * 32 + c)];
  __syncthreads();
  for (int rr = r; rr < 32; rr += 8)
    out[(size_t)(tn * 32 + rr) * K + (tk * 32 + c)] = f32_to_bf16(tile[c][rr]);
}

// x (N x 513) -> A0 bf16 (N x 512), labels int, class histogram
__global__ __launch_bounds__(256)
void prep_x(const float* __restrict__ x, u16* __restrict__ A0,
            int* __restrict__ labels, int* __restrict__ counts)
{
  const int g = blockIdx.x * 256 + threadIdx.x;
  const int T = 4096 * 256;
  for (int e = g; e < NROWS * DIN; e += T) {
    const int i = e >> 9, k = e & 511;
    A0[e] = f32_to_bf16(x[(size_t)i * 513 + 1 + k]);
  }
  if (g < NROWS) {
    const int l = (int)x[(size_t)g * 513];
    labels[g] = l;
    atomicAdd(&counts[l], 1);
  }
}

__global__ void make_offsets(const int* __restrict__ counts,
                             int* __restrict__ offs, int* __restrict__ cursors)
{
  if (threadIdx.x == 0) {
    int s = 0;
    for (int c = 0; c < NCLS; ++c) { offs[c] = s; cursors[c] = s; s += counts[c]; }
    offs[NCLS] = s;
  }
}

__global__ __launch_bounds__(256)
void scatter_idx(const int* __restrict__ labels, int* __restrict__ cursors,
                 int* __restrict__ idx)
{
  const int i = blockIdx.x * 256 + threadIdx.x;
  if (i < NROWS) {
    const int c = labels[i];
    const int p = atomicAdd(&cursors[c], 1);
    idx[p] = i;
  }
}

// Per-class sums: Ssum[c] = sum of ||c_i||^2, vsum[c][k] = sum of c_i[k]
__global__ __launch_bounds__(256)
void stats_kernel(const float* __restrict__ Ef, const int* __restrict__ labels,
                  float* __restrict__ vsum, float* __restrict__ Ssum)
{
  __shared__ float lv[NCLS * NCONS];
  __shared__ float ls[NCLS];
  const int tid = threadIdx.x;
  for (int i = tid; i < NCLS * NCONS; i += 256) lv[i] = 0.f;
  if (tid < NCLS) ls[tid] = 0.f;
  __syncthreads();
  const int row = blockIdx.x * 256 + tid;
  const int c = labels[row];
  const float* e = Ef + (size_t)row * EMBN + 2;
  float sq = 0.f;
  for (int k = 0; k < NCONS; ++k) {
    const float v = e[k];
    sq += v * v;
    atomicAdd(&lv[c * NCONS + k], v);
  }
  atomicAdd(&ls[c], sq);
  __syncthreads();
  for (int i = tid; i < NCLS * NCONS; i += 256) atomicAdd(&vsum[i], lv[i]);
  if (tid < NCLS) atomicAdd(&Ssum[tid], ls[tid]);
}

// Same-class pairwise hinge: sum over i!=j same class of max(0, margin - D)
// 64x64 tile-pairs per block, 4x4 per thread, fp32 in LDS (stride 67: 2-way
// bank aliasing only, which is free).
__global__ __launch_bounds__(256)
void pairwise(const float* __restrict__ Ef, const int* __restrict__ idx,
              const int* __restrict__ offs, float* __restrict__ pair_sum)
{
  const int cls = blockIdx.y;
  const int ti = blockIdx.x >> 4, tj = blockIdx.x & 15;
  const int start = offs[cls];
  const int n = offs[cls + 1] - start;
  if (ti * 64 >= n || tj * 64 >= n) return;   // block-uniform

  __shared__ float Ci[64 * 67];
  __shared__ float Cj[64 * 67];
  const int tid = threadIdx.x;
  for (int e = tid; e < 64 * 64; e += 256) {
    const int row = e >> 6, col = e & 63;
    if (col < NCONS) {
      const int gi = ti * 64 + row, gj = tj * 64 + row;
      Ci[row * 67 + col] = (gi < n) ? Ef[(size_t)idx[start + gi] * EMBN + 2 + col] : 0.f;
      Cj[row * 67 + col] = (gj < n) ? Ef[(size_t)idx[start + gj] * EMBN + 2 + col] : 0.f;
    }
  }
  __syncthreads();

  const int ia = tid >> 4, jb = tid & 15;
  float s[4][4] = {};
  const float* ci = &Ci[ia * 4 * 67];
  const float* cj = &Cj[jb * 4 * 67];
  for (int k = 0; k < NCONS; ++k) {
    const float a0 = ci[k], a1 = ci[67 + k], a2 = ci[134 + k], a3 = ci[201 + k];
    const float b0 = cj[k], b1 = cj[67 + k], b2 = cj[134 + k], b3 = cj[201 + k];
    float d;
    d = a0 - b0; s[0][0] += d * d;  d = a0 - b1; s[0][1] += d * d;
    d = a0 - b2; s[0][2] += d * d;  d = a0 - b3; s[0][3] += d * d;
    d = a1 - b0; s[1][0] += d * d;  d = a1 - b1; s[1][1] += d * d;
    d = a1 - b2; s[1][2] += d * d;  d = a1 - b3; s[1][3] += d * d;
    d = a2 - b0; s[2][0] += d * d;  d = a2 - b1; s[2][1] += d * d;
    d = a2 - b2; s[2][2] += d * d;  d = a2 - b3; s[2][3] += d * d;
    d = a3 - b0; s[3][0] += d * d;  d = a3 - b1; s[3][1] += d * d;
    d = a3 - b2; s[3][2] += d * d;  d = a3 - b3; s[3][3] += d * d;
  }

  float local = 0.f;
#pragma unroll
  for (int r = 0; r < 4; ++r)
#pragma unroll
    for (int q = 0; q < 4; ++q) {
      const int gi = ti * 64 + ia * 4 + r;
      const int gj = tj * 64 + jb * 4 + q;
      const float D = s[r][q] * (1.f / 62.f);
      if (gi < n && gj < n && gi != gj) local += fmaxf(0.f, MARGINF - D);
    }

  __shared__ float red[256];
  red[tid] = local;
  __syncthreads();
  for (int st = 128; st > 0; st >>= 1) {
    if (tid < st) red[tid] += red[tid + st];
    __syncthreads();
  }
  if (tid == 0) atomicAdd(pair_sum, red[0]);
}

__device__ __forceinline__ double block_reduce_d(double v, double* red, int tid) {
  red[tid] = v;
  __syncthreads();
  for (int st = 128; st > 0; st >>= 1) {
    if (tid < st) red[tid] += red[tid + st];
    __syncthreads();
  }
  const double r = red[0];
  __syncthreads();
  return r;
}

// C_sim (factored, no N^2) and C_diff from pair_sum + analytic diagonal.
__global__ __launch_bounds__(256)
void finalize(const float* __restrict__ vsum, const float* __restrict__ Ssum,
              const int* __restrict__ counts, const float* __restrict__ pair_sum,
              float* __restrict__ out2)
{
  const int tid = threadIdx.x;
  __shared__ double red[256];

  double v = 0.0;
  if (tid < NCLS) v = (double)Ssum[tid] * (double)(NROWS - counts[tid]);
  const double t1 = block_reduce_d(v, red, tid);            // sum_c S_c (N - n_c)

  v = 0.0;
  if (tid < NCLS) { const double nc = (double)counts[tid]; v = nc * nc; }
  const double n_same = block_reduce_d(v, red, tid);        // sum n_c^2

  v = 0.0;
  for (int i = tid; i < NCLS * NCONS; i += 256) { const double w = vsum[i]; v += w * w; }
  const double t2 = block_reduce_d(v, red, tid);            // sum_c |v_c|^2

  v = 0.0;
  if (tid < NCONS) {
    double Vk = 0.0;
    for (int c = 0; c < NCLS; ++c) Vk += (double)vsum[c * NCONS + tid];
    v = Vk * Vk;
  }
  const double t3 = block_reduce_d(v, red, tid);            // |V|^2

  if (tid == 0) {
    const double n_diff = (double)NROWS * (double)NROWS - n_same;
    const double sim = 2.0 * t1 - 2.0 * (t3 - t2);
    const double C_sim = sim / 62.0 / (n_diff + 1.0);
    const double C_diff = ((double)pair_sum[0] + (double)NROWS * (double)MARGINF)
                          / (n_same + 1.0);
    out2[0] = (float)C_sim;
    out2[1] = (float)C_diff;
  }
}

// ---------------------------------------------------------------------------
extern "C" void kernel_launch(void* const* d_in, const int* in_sizes, int n_in,
                              void* d_out, int out_size, void* d_ws, size_t ws_size,
                              hipStream_t stream)
{
  const float* x  = (const float*)d_in[0];
  const float* W1 = (const float*)d_in[1];
  const float* b1 = (const float*)d_in[2];
  const float* W2 = (const float*)d_in[3];
  const float* b2 = (const float*)d_in[4];
  const float* W3 = (const float*)d_in[5];
  const float* b3 = (const float*)d_in[6];
  const float* W4 = (const float*)d_in[7];
  const float* b4 = (const float*)d_in[8];
  float* out = (float*)d_out;

  char* ws = (char*)d_ws;
  const size_t MB = 1ull << 20;
  u16* W1T    = (u16*)(ws + 0);                    // 1 MB  (1024 x 512)
  u16* W4T    = (u16*)(ws + 1 * MB);               // 1 MB  (512 x 1024)
  u16* W2T    = (u16*)(ws + 2 * MB);               // 128 KB (64 x 1024)
  u16* W3T    = (u16*)(ws + 2 * MB + 128 * 1024);  // 128 KB (1024 x 64)
  int* labels = (int*)(ws + 2 * MB + 256 * 1024);  // 32 KB
  int* idx    = (int*)(ws + 2 * MB + 288 * 1024);  // 32 KB
  float* acc  = (float*)(ws + 2 * MB + 320 * 1024);// 16 KB slab
  int*   counts  = (int*)acc;                      // [0,16)
  int*   offs    = counts + 16;                    // [16,33)
  int*   cursors = counts + 64;                    // [64,80)
  float* Ssum    = (float*)(counts + 96);          // 16
  float* psum    = (float*)(counts + 128);         // 1
  float* vsum    = (float*)(counts + 256);         // 992
  float* Ef   = (float*)(ws + 3 * MB);             // 2 MB  (8192 x 64 f32)
  u16* Ebf    = (u16*)(ws + 5 * MB);               // 1 MB  (8192 x 64 bf16)
  u16* A0     = (u16*)(ws + 6 * MB);               // 8 MB  (8192 x 512 bf16)
  u16* H      = (u16*)(ws + 14 * MB);              // 16 MB (8192 x 1024); reused as T
  (void)in_sizes; (void)n_in; (void)out_size; (void)ws_size;

  prep_weights<<<dim3(1152), dim3(256), 0, stream>>>(W1, W4, W2, W3,
                                                     W1T, W4T, W2T, W3T, acc, 2048);
  prep_x<<<dim3(4096), dim3(256), 0, stream>>>(x, A0, labels, counts);
  make_offsets<<<dim3(1), dim3(64), 0, stream>>>(counts, offs, cursors);
  scatter_idx<<<dim3(32), dim3(256), 0, stream>>>(labels, cursors, idx);

  // H = tanh(A0 @ W1 + b1)           M=8192 N=1024 K=512
  gemm_bt<128, 64, true, false, true><<<dim3(16, 64), dim3(256), 0, stream>>>(
      A0, W1T, b1, (float*)nullptr, H, 1024, 512);
  // E = H @ W2 + b2                  M=8192 N=64 K=1024  (f32 + bf16 out)
  gemm_bt<64, 64, false, true, true><<<dim3(1, 128), dim3(256), 0, stream>>>(
      H, W2T, b2, Ef, Ebf, 64, 1024);
  // T = tanh(E @ W3 + b3)            M=8192 N=1024 K=64  (overwrites H)
  gemm_bt<128, 64, true, false, true><<<dim3(16, 64), dim3(256), 0, stream>>>(
      Ebf, W3T, b3, (float*)nullptr, H, 1024, 64);
  // decoded = T @ W4 + b4            M=8192 N=512 K=1024 (f32 -> d_out)
  gemm_bt<128, 64, false, true, false><<<dim3(8, 64), dim3(256), 0, stream>>>(
      H, W4T, b4, out, (u16*)nullptr, 512, 1024);

  stats_kernel<<<dim3(32), dim3(256), 0, stream>>>(Ef, labels, vsum, Ssum);
  pairwise<<<dim3(256, 16), dim3(256), 0, stream>>>(Ef, idx, offs, psum);
  finalize<<<dim3(1), dim3(256), 0, stream>>>(vsum, Ssum, counts, psum,
                                              out + (size_t)NROWS * DIN);
}